// Round 8
// baseline (667.334 us; speedup 1.0000x reference)
//
#include <hip/hip_runtime.h>
#include <hip/hip_bf16.h>

#define BB 4
#define CPG 48
#define HH 128
#define WW2 128
#define PP 16384
#define DIM 384
#define DIM3 1152

typedef unsigned short u16;
typedef __attribute__((ext_vector_type(8))) short bf16x8;
typedef __attribute__((ext_vector_type(4))) float f32x4;

__device__ __forceinline__ float bf2f(u16 u) {
    return __uint_as_float(((unsigned int)u) << 16);
}
__device__ __forceinline__ u16 f2bf(float f) {
    unsigned int u = __float_as_uint(f);
    unsigned int r = (u + 0x7fffu + ((u >> 16) & 1u)) >> 16;
    return (u16)r;
}

// LDS swizzle: rows are 128B; XOR the 16B-slot index with (row&7) to spread banks
__device__ __forceinline__ int swz(int row, int kb) {
    return row * 128 + (kb ^ ((row & 7) << 4));
}

// ---------------- convert w_qkv fp32 -> bf16
__global__ __launch_bounds__(256) void k_wcvt(const float* __restrict__ w,
                                              u16* __restrict__ wbf)
{
    const int i4 = (blockIdx.x * 256 + threadIdx.x) * 4;
    float4 v = *reinterpret_cast<const float4*>(w + i4);
    ushort4 s;
    s.x = f2bf(v.x); s.y = f2bf(v.y); s.z = f2bf(v.z); s.w = f2bf(v.w);
    *reinterpret_cast<ushort4*>(wbf + i4) = s;
}

// ---------------- transpose x [b][k=384][p] fp32 -> Xt [b][p][k=384] bf16
__global__ __launch_bounds__(256) void k_tr_x(const float* __restrict__ x,
                                              u16* __restrict__ xt)
{
    const int b = blockIdx.z;
    const int k0 = blockIdx.y * 64;
    const int p0 = blockIdx.x * 64;
    const int t = threadIdx.x;
    __shared__ u16 T[64][68];

    const int kl = t >> 4;          // 0..15
    const int pl = (t & 15) * 4;    // 0..60
#pragma unroll
    for (int ks = 0; ks < 4; ++ks) {
        const int k = ks * 16 + kl;
        float4 v = *reinterpret_cast<const float4*>(&x[((size_t)b * DIM + k0 + k) * PP + p0 + pl]);
        ushort4 s;
        s.x = f2bf(v.x); s.y = f2bf(v.y); s.z = f2bf(v.z); s.w = f2bf(v.w);
        *reinterpret_cast<ushort4*>(&T[k][pl]) = s;
    }
    __syncthreads();
    const int pr = t >> 2;          // 0..63
    const int kg = (t & 3) * 16;    // 0,16,32,48
    __align__(16) u16 tmp[16];
#pragma unroll
    for (int j = 0; j < 16; ++j) tmp[j] = T[kg + j][pr];
    u16* dst = xt + ((size_t)b * PP + p0 + pr) * DIM + k0 + kg;
    *reinterpret_cast<uint4*>(dst)     = *reinterpret_cast<uint4*>(tmp);
    *reinterpret_cast<uint4*>(dst + 8) = *reinterpret_cast<uint4*>(tmp + 8);
}

// ---------------- transpose v part of y2 [b][768+c][p] bf16 -> Vt [b][p][c=384] bf16
__global__ __launch_bounds__(256) void k_tr_v(const u16* __restrict__ y2,
                                              u16* __restrict__ vt)
{
    const int b = blockIdx.z;
    const int c0 = blockIdx.y * 64;
    const int p0 = blockIdx.x * 64;
    const int t = threadIdx.x;
    __shared__ u16 T[64][68];

    const int cl = t >> 4;
    const int pl = (t & 15) * 4;
#pragma unroll
    for (int cs = 0; cs < 4; ++cs) {
        const int c = cs * 16 + cl;
        ushort4 v = *reinterpret_cast<const ushort4*>(
            &y2[((size_t)b * DIM3 + 2 * DIM + c0 + c) * PP + p0 + pl]);
        *reinterpret_cast<ushort4*>(&T[c][pl]) = v;
    }
    __syncthreads();
    const int pr = t >> 2;
    const int kg = (t & 3) * 16;
    __align__(16) u16 tmp[16];
#pragma unroll
    for (int j = 0; j < 16; ++j) tmp[j] = T[kg + j][pr];
    u16* dst = vt + ((size_t)b * PP + p0 + pr) * DIM + c0 + kg;
    *reinterpret_cast<uint4*>(dst)     = *reinterpret_cast<uint4*>(tmp);
    *reinterpret_cast<uint4*>(dst + 8) = *reinterpret_cast<uint4*>(tmp + 8);
}

// ---------------- MFMA GEMM: C[b][co][p] = sum_k A[(b)][co][k] * Bt[b][p][k]
// MODE 0: += bias, write bf16 ybf.  MODE 1: += bias + xres, write fp32 fout.
// 1D grid with XCD-locality swizzle: each XCD owns 16 contiguous p-tiles,
// y (co-tile) cycles fastest, then batch -> B-panels become L2-resident.
template<int MODE>
__global__ __launch_bounds__(256) void k_gemm(const u16* __restrict__ A, int aStride,
                                              const u16* __restrict__ Bt,
                                              const float* __restrict__ bias,
                                              u16* __restrict__ ybf,
                                              const float* __restrict__ xres,
                                              float* __restrict__ fout,
                                              int nyTiles)
{
    const int bid = blockIdx.x;
    const int xcd = bid & 7;
    const int r1  = bid >> 3;
    const int px  = xcd * 16 + (r1 & 15);   // p-tile 0..127
    const int r2  = r1 >> 4;
    const int b   = r2 / nyTiles;           // batch
    const int yt  = r2 - b * nyTiles;       // co-tile
    const int co0 = yt * 128;
    const int p0  = px * 128;

    const int t   = threadIdx.x;
    const int l   = t & 63;
    const int wid = t >> 6;
    const int wr  = wid >> 1;      // 0..1 -> row half
    const int wc  = wid & 1;       // 0..1 -> col half
    const int lr  = l & 15;
    const int lg  = l >> 4;        // 0..3

    __shared__ __align__(16) char lds[32768];
    char* AsB = lds;               // [128 rows][64 k] bf16, swizzled
    char* BsB = lds + 16384;

    f32x4 acc[4][4];
#pragma unroll
    for (int m = 0; m < 4; ++m)
#pragma unroll
        for (int n = 0; n < 4; ++n) acc[m][n] = (f32x4){0.f, 0.f, 0.f, 0.f};

    const u16* Ab  = A  + (size_t)b * aStride;
    const u16* Btb = Bt + (size_t)b * PP * DIM;

    const int srow = t >> 1;       // 0..127
    const int shalf = t & 1;       // 0..1 (32 bf16 = 64B)

    for (int k0 = 0; k0 < DIM; k0 += 64) {
        const u16* sa = Ab  + (size_t)(co0 + srow) * DIM + k0 + shalf * 32;
        const u16* sb = Btb + (size_t)(p0  + srow) * DIM + k0 + shalf * 32;
        uint4 ra[2], rb[2];
#pragma unroll
        for (int i = 0; i < 2; ++i) {
            ra[i] = *reinterpret_cast<const uint4*>(sa + i * 8);
            rb[i] = *reinterpret_cast<const uint4*>(sb + i * 8);
        }
        uint4 ra2[2], rb2[2];
#pragma unroll
        for (int i = 0; i < 2; ++i) {
            ra2[i] = *reinterpret_cast<const uint4*>(sa + 16 + i * 8);
            rb2[i] = *reinterpret_cast<const uint4*>(sb + 16 + i * 8);
        }
        if (k0) __syncthreads();
#pragma unroll
        for (int i = 0; i < 2; ++i) {
            const int kb = shalf * 64 + i * 16;
            *reinterpret_cast<uint4*>(AsB + swz(srow, kb)) = ra[i];
            *reinterpret_cast<uint4*>(BsB + swz(srow, kb)) = rb[i];
        }
#pragma unroll
        for (int i = 0; i < 2; ++i) {
            const int kb = shalf * 64 + 32 + i * 16;
            *reinterpret_cast<uint4*>(AsB + swz(srow, kb)) = ra2[i];
            *reinterpret_cast<uint4*>(BsB + swz(srow, kb)) = rb2[i];
        }
        __syncthreads();

#pragma unroll
        for (int kk = 0; kk < 64; kk += 32) {
            const int kbyte = kk * 2 + lg * 16;
            bf16x8 av[4], bv[4];
#pragma unroll
            for (int m = 0; m < 4; ++m) {
                const int row = wr * 64 + m * 16 + lr;
                av[m] = *reinterpret_cast<const bf16x8*>(AsB + swz(row, kbyte));
            }
#pragma unroll
            for (int n = 0; n < 4; ++n) {
                const int row = wc * 64 + n * 16 + lr;
                bv[n] = *reinterpret_cast<const bf16x8*>(BsB + swz(row, kbyte));
            }
#pragma unroll
            for (int m = 0; m < 4; ++m)
#pragma unroll
                for (int n = 0; n < 4; ++n)
                    acc[m][n] = __builtin_amdgcn_mfma_f32_16x16x32_bf16(
                        av[m], bv[n], acc[m][n], 0, 0, 0);
        }
    }

    // bias per (m, r): row = wr*64 + m*16 + lg*4 + r
    float bias_r[4][4];
#pragma unroll
    for (int m = 0; m < 4; ++m)
#pragma unroll
        for (int r = 0; r < 4; ++r)
            bias_r[m][r] = bias[co0 + wr * 64 + m * 16 + lg * 4 + r];

    if (MODE == 0) {
        __syncthreads();
        u16* Cs = reinterpret_cast<u16*>(lds);
#pragma unroll
        for (int m = 0; m < 4; ++m)
#pragma unroll
            for (int n = 0; n < 4; ++n)
#pragma unroll
                for (int r = 0; r < 4; ++r) {
                    const int row = wr * 64 + m * 16 + lg * 4 + r;
                    const int col = wc * 64 + n * 16 + lr;
                    Cs[row * 128 + col] = f2bf(acc[m][n][r] + bias_r[m][r]);
                }
        __syncthreads();
        // coalesced store: 16 lanes cover one 256B row segment; a wave writes
        // 4 full rows per instruction (1 KB contiguous groups)
        const int rr = t >> 4;          // 0..15
        const int cs = (t & 15) * 8;    // u16 col
#pragma unroll
        for (int j = 0; j < 8; ++j) {
            const int row = j * 16 + rr;
            *reinterpret_cast<uint4*>(&ybf[((size_t)b * DIM3 + co0 + row) * PP + p0 + cs]) =
                *reinterpret_cast<const uint4*>(&Cs[row * 128 + cs]);
        }
    } else {
        // fp32 epilogue via LDS in two 64-row half-passes; rows 0-63 owned by
        // waves wr==0, rows 64-127 by wr==1. [64][128] fp32 = 32768 B.
        float* Cf = reinterpret_cast<float*>(lds);
#pragma unroll
        for (int h = 0; h < 2; ++h) {
            __syncthreads();
            if (wr == h) {
#pragma unroll
                for (int m = 0; m < 4; ++m)
#pragma unroll
                    for (int n = 0; n < 4; ++n)
#pragma unroll
                        for (int r = 0; r < 4; ++r) {
                            const int lrow = m * 16 + lg * 4 + r;
                            const int col = wc * 64 + n * 16 + lr;
                            Cf[lrow * 128 + col] = acc[m][n][r] + bias_r[m][r];
                        }
            }
            __syncthreads();
            // 32 lanes cover one 512B fp32 row; 8 rows per round, 8 rounds
            const int rr = t >> 5;          // 0..7
            const int cc = (t & 31) * 4;    // fp32 col
#pragma unroll
            for (int j = 0; j < 8; ++j) {
                const int lrow = j * 8 + rr;
                const int grow = h * 64 + lrow;
                const size_t idx = ((size_t)b * DIM + co0 + grow) * PP + p0 + cc;
                float4 xr = *reinterpret_cast<const float4*>(&xres[idx]);
                float4 cv = *reinterpret_cast<const float4*>(&Cf[lrow * 128 + cc]);
                cv.x += xr.x; cv.y += xr.y; cv.z += xr.z; cv.w += xr.w;
                *reinterpret_cast<float4*>(&fout[idx]) = cv;
            }
        }
    }
}

// ---------------- depthwise 3x3 + bias -> bf16 y2
__global__ __launch_bounds__(256) void k_dw(const u16* __restrict__ y1,
                                            const float* __restrict__ wdw,
                                            const float* __restrict__ bdw,
                                            u16* __restrict__ y2)
{
    const int b  = blockIdx.z;
    const int ch = blockIdx.y;
    const int p  = (blockIdx.x * 256 + (int)threadIdx.x) * 8;
    const int row = p >> 7;
    const int col = p & 127;
    const size_t ib = ((size_t)b * DIM3 + ch) * PP;
    const u16* img = y1 + ib;

    float w9[9];
#pragma unroll
    for (int i = 0; i < 9; ++i) w9[i] = wdw[ch * 9 + i];
    const float bv = bdw[ch];

    float vr[3][10];
#pragma unroll
    for (int dy = 0; dy < 3; ++dy) {
        const int r = row + dy - 1;
        if (r >= 0 && r < HH) {
            const u16* rp = img + r * WW2 + col;
            union { int4 v; u16 u[8]; } cc;
            cc.v = *reinterpret_cast<const int4*>(rp);
#pragma unroll
            for (int j = 0; j < 8; ++j) vr[dy][j + 1] = bf2f(cc.u[j]);
            vr[dy][0] = (col > 0) ? bf2f(rp[-1]) : 0.f;
            vr[dy][9] = (col + 8 < WW2) ? bf2f(rp[8]) : 0.f;
        } else {
#pragma unroll
            for (int j = 0; j < 10; ++j) vr[dy][j] = 0.f;
        }
    }
    union { int4 v; u16 u[8]; } ou;
#pragma unroll
    for (int j = 0; j < 8; ++j) {
        float a = bv;
#pragma unroll
        for (int dy = 0; dy < 3; ++dy)
#pragma unroll
            for (int dx = 0; dx < 3; ++dx)
                a = fmaf(w9[dy * 3 + dx], vr[dy][j + dx], a);
        ou.u[j] = f2bf(a);
    }
    *reinterpret_cast<int4*>(y2 + ib + p) = ou.v;
}

// ---------------- Gram-matrix partials (q.k, q.q, k.k) per batch
__global__ __launch_bounds__(256) void k_dots(const u16* __restrict__ y2,
                                              float* __restrict__ partial)
{
    const int b  = blockIdx.z;
    const int cy = blockIdx.y;
    const int c0 = cy * 24;
    const int p2 = (blockIdx.x * 256 + (int)threadIdx.x) * 2;
    const u16* qb = y2 + (size_t)b * DIM3 * PP + p2;
    const u16* kb = qb + (size_t)DIM * PP;

    float qk[64], qq[8], ks[8];
#pragma unroll
    for (int i = 0; i < 64; ++i) qk[i] = 0.f;
#pragma unroll
    for (int i = 0; i < 8; ++i) { qq[i] = 0.f; ks[i] = 0.f; }

    for (int c = c0; c < c0 + 24; ++c) {
        float q0[8], q1[8], k0[8], k1[8];
#pragma unroll
        for (int n = 0; n < 8; ++n) {
            const unsigned int qv = *reinterpret_cast<const unsigned int*>(qb + (size_t)(n * CPG + c) * PP);
            q0[n] = __uint_as_float(qv << 16);
            q1[n] = __uint_as_float(qv & 0xffff0000u);
            const unsigned int kv = *reinterpret_cast<const unsigned int*>(kb + (size_t)(n * CPG + c) * PP);
            k0[n] = __uint_as_float(kv << 16);
            k1[n] = __uint_as_float(kv & 0xffff0000u);
        }
#pragma unroll
        for (int n = 0; n < 8; ++n) {
#pragma unroll
            for (int m = 0; m < 8; ++m)
                qk[n * 8 + m] += q0[n] * k0[m] + q1[n] * k1[m];
            qq[n] += q0[n] * q0[n] + q1[n] * q1[n];
            ks[n] += k0[n] * k0[n] + k1[n] * k1[n];
        }
    }
    const int wave = (int)threadIdx.x >> 6;
    const int lane = (int)threadIdx.x & 63;
    const size_t rowidx = (size_t)((((b * 2 + cy) * 32 + blockIdx.x) * 4 + wave)) * 80;
#pragma unroll
    for (int i = 0; i < 80; ++i) {
        float v = (i < 64) ? qk[i] : ((i < 72) ? qq[i - 64] : ks[i - 72]);
        v += __shfl_down(v, 32);
        v += __shfl_down(v, 16);
        v += __shfl_down(v, 8);
        v += __shfl_down(v, 4);
        v += __shfl_down(v, 2);
        v += __shfl_down(v, 1);
        if (lane == 0) partial[rowidx + i] = v;
    }
}

// ---------------- reduce partials, normalize, softmax -> attn[b][8][8]
__global__ __launch_bounds__(128) void k_attn(const float* __restrict__ partial,
                                              const float* __restrict__ temp,
                                              float* __restrict__ attn)
{
    const int b = blockIdx.x;
    const int t = threadIdx.x;
    __shared__ float dots[80];
    __shared__ float sc[8][8];
    if (t < 80) {
        float s = 0.f;
        for (int i = 0; i < 256; ++i)
            s += partial[((size_t)b * 256 + i) * 80 + t];
        dots[t] = s;
    }
    __syncthreads();
    if (t < 64) {
        const int n = t >> 3, m = t & 7;
        const float qn = fmaxf(sqrtf(dots[64 + n]), 1e-12f);
        const float km = fmaxf(sqrtf(dots[72 + m]), 1e-12f);
        sc[n][m] = dots[n * 8 + m] / (qn * km) * temp[0];
    }
    __syncthreads();
    if (t < 8) {
        float mx = -3.0e38f;
#pragma unroll
        for (int m = 0; m < 8; ++m) mx = fmaxf(mx, sc[t][m]);
        float e[8], s = 0.f;
#pragma unroll
        for (int m = 0; m < 8; ++m) { e[m] = expf(sc[t][m] - mx); s += e[m]; }
        const float inv = 1.f / s;
#pragma unroll
        for (int m = 0; m < 8; ++m) attn[(b * 8 + t) * 8 + m] = e[m] * inv;
    }
}

// ---------------- Weff[b][co][m*48+c] = sum_n wproj[co][n*48+c]*attn[n][m]  (bf16 out)
__global__ __launch_bounds__(128) void k_weff(const float* __restrict__ attn,
                                              const float* __restrict__ wproj,
                                              u16* __restrict__ weff)
{
    const int b  = blockIdx.y;
    const int co = blockIdx.x;
    const int t  = threadIdx.x;
    __shared__ float a[64];
    if (t < 64) a[t] = attn[b * 64 + t];
    __syncthreads();
    const float* wrow = wproj + (size_t)co * DIM;
    u16* wout = weff + ((size_t)b * DIM + co) * DIM;
    for (int i = t; i < DIM; i += 128) {
        const int m = i / CPG;
        const int c = i - m * CPG;
        float s = 0.f;
#pragma unroll
        for (int n = 0; n < 8; ++n) s += wrow[n * CPG + c] * a[n * 8 + m];
        wout[i] = f2bf(s);
    }
}

extern "C" void kernel_launch(void* const* d_in, const int* in_sizes, int n_in,
                              void* d_out, int out_size, void* d_ws, size_t ws_size,
                              hipStream_t stream)
{
    const float* x      = (const float*)d_in[0];
    const float* temp   = (const float*)d_in[1];
    const float* w_qkv  = (const float*)d_in[2];
    const float* b_qkv  = (const float*)d_in[3];
    const float* w_dw   = (const float*)d_in[4];
    const float* b_dw   = (const float*)d_in[5];
    const float* w_proj = (const float*)d_in[6];
    const float* b_proj = (const float*)d_in[7];
    float* out = (float*)d_out;

    char* ws = (char*)d_ws;
    const size_t SZ_QKV = (size_t)BB * DIM3 * PP * sizeof(u16);  // 150,994,944
    const size_t SZ_XT  = (size_t)BB * PP * DIM * sizeof(u16);   //  50,331,648

    // region 0: [0, SZ_QKV)
    u16* y1 = (u16*)ws;                           // k_gemm<0> -> k_dw, then dead
    float* partial = (float*)ws;                  // 327,680 B (after k_dw)
    float* attn    = (float*)(ws + 327680);       // 1,024 B
    u16*   weffb   = (u16*)(ws + 331776);         // 1,179,648 B (ends 1,511,424)
    u16*   vt      = (u16*)(ws + 2097152);        // 50,331,648 B (ends ~52.4 MB)

    // region 1: [SZ_QKV, SZ_QKV + SZ_QKV)
    u16* y2  = (u16*)(ws + SZ_QKV);               // k_dw onward
    u16* xt  = (u16*)(ws + SZ_QKV);               // pre-k_dw only (aliased, dead before y2 write)
    u16* wbf = (u16*)(ws + SZ_QKV + SZ_XT);       // 884,736 B (pre-k_dw only)

    k_wcvt<<<dim3(DIM3 * DIM / 1024), 256, 0, stream>>>(w_qkv, wbf);
    k_tr_x<<<dim3(PP / 64, DIM / 64, BB), 256, 0, stream>>>(x, xt);
    k_gemm<0><<<dim3(128 * 9 * BB), 256, 0, stream>>>(
        wbf, 0, xt, b_qkv, y1, nullptr, nullptr, 9);
    k_dw<<<dim3(PP / 2048, DIM3, BB), 256, 0, stream>>>(y1, w_dw, b_dw, y2);
    k_dots<<<dim3(32, 2, BB), 256, 0, stream>>>(y2, partial);
    k_attn<<<dim3(BB), 128, 0, stream>>>(partial, temp, attn);
    k_weff<<<dim3(DIM, BB), 128, 0, stream>>>(attn, w_proj, weffb);
    k_tr_v<<<dim3(PP / 64, DIM / 64, BB), 256, 0, stream>>>(y2, vt);
    k_gemm<1><<<dim3(128 * 3 * BB), 256, 0, stream>>>(
        weffb, DIM * DIM, vt, b_proj, nullptr, x, out, 3);
}

// Round 9
// 388.182 us; speedup vs baseline: 1.7191x; 1.7191x over previous
//
#include <hip/hip_runtime.h>
#include <hip/hip_bf16.h>

#define BB 4
#define CPG 48
#define HH 128
#define WW2 128
#define PP 16384
#define DIM 384
#define DIM3 1152

typedef unsigned short u16;
typedef __attribute__((ext_vector_type(8))) short bf16x8;
typedef __attribute__((ext_vector_type(4))) float f32x4;

__device__ __forceinline__ float bf2f(u16 u) {
    return __uint_as_float(((unsigned int)u) << 16);
}
__device__ __forceinline__ u16 f2bf(float f) {
    unsigned int u = __float_as_uint(f);
    unsigned int r = (u + 0x7fffu + ((u >> 16) & 1u)) >> 16;
    return (u16)r;
}

// LDS swizzle: rows are 128B; XOR the 16B-slot index with (row&7) to spread banks
__device__ __forceinline__ int swz(int row, int kb) {
    return row * 128 + (kb ^ ((row & 7) << 4));
}

// async global->LDS, 16B per lane; LDS dest = wave-uniform base + lane*16
__device__ __forceinline__ void gld_lds16(const u16* g, char* l) {
    __builtin_amdgcn_global_load_lds(
        (const __attribute__((address_space(1))) void*)g,
        (__attribute__((address_space(3))) void*)l, 16, 0, 0);
}

// ---------------- convert w_qkv fp32 -> bf16
__global__ __launch_bounds__(256) void k_wcvt(const float* __restrict__ w,
                                              u16* __restrict__ wbf)
{
    const int i4 = (blockIdx.x * 256 + threadIdx.x) * 4;
    float4 v = *reinterpret_cast<const float4*>(w + i4);
    ushort4 s;
    s.x = f2bf(v.x); s.y = f2bf(v.y); s.z = f2bf(v.z); s.w = f2bf(v.w);
    *reinterpret_cast<ushort4*>(wbf + i4) = s;
}

// ---------------- transpose x [b][k=384][p] fp32 -> Xt [b][p][k=384] bf16
__global__ __launch_bounds__(256) void k_tr_x(const float* __restrict__ x,
                                              u16* __restrict__ xt)
{
    const int b = blockIdx.z;
    const int k0 = blockIdx.y * 64;
    const int p0 = blockIdx.x * 64;
    const int t = threadIdx.x;
    __shared__ u16 T[64][68];

    const int kl = t >> 4;          // 0..15
    const int pl = (t & 15) * 4;    // 0..60
#pragma unroll
    for (int ks = 0; ks < 4; ++ks) {
        const int k = ks * 16 + kl;
        float4 v = *reinterpret_cast<const float4*>(&x[((size_t)b * DIM + k0 + k) * PP + p0 + pl]);
        ushort4 s;
        s.x = f2bf(v.x); s.y = f2bf(v.y); s.z = f2bf(v.z); s.w = f2bf(v.w);
        *reinterpret_cast<ushort4*>(&T[k][pl]) = s;
    }
    __syncthreads();
    const int pr = t >> 2;          // 0..63
    const int kg = (t & 3) * 16;    // 0,16,32,48
    __align__(16) u16 tmp[16];
#pragma unroll
    for (int j = 0; j < 16; ++j) tmp[j] = T[kg + j][pr];
    u16* dst = xt + ((size_t)b * PP + p0 + pr) * DIM + k0 + kg;
    *reinterpret_cast<uint4*>(dst)     = *reinterpret_cast<uint4*>(tmp);
    *reinterpret_cast<uint4*>(dst + 8) = *reinterpret_cast<uint4*>(tmp + 8);
}

// ---------------- transpose v part of y2 [b][768+c][p] bf16 -> Vt [b][p][c=384] bf16
__global__ __launch_bounds__(256) void k_tr_v(const u16* __restrict__ y2,
                                              u16* __restrict__ vt)
{
    const int b = blockIdx.z;
    const int c0 = blockIdx.y * 64;
    const int p0 = blockIdx.x * 64;
    const int t = threadIdx.x;
    __shared__ u16 T[64][68];

    const int cl = t >> 4;
    const int pl = (t & 15) * 4;
#pragma unroll
    for (int cs = 0; cs < 4; ++cs) {
        const int c = cs * 16 + cl;
        ushort4 v = *reinterpret_cast<const ushort4*>(
            &y2[((size_t)b * DIM3 + 2 * DIM + c0 + c) * PP + p0 + pl]);
        *reinterpret_cast<ushort4*>(&T[c][pl]) = v;
    }
    __syncthreads();
    const int pr = t >> 2;
    const int kg = (t & 3) * 16;
    __align__(16) u16 tmp[16];
#pragma unroll
    for (int j = 0; j < 16; ++j) tmp[j] = T[kg + j][pr];
    u16* dst = vt + ((size_t)b * PP + p0 + pr) * DIM + c0 + kg;
    *reinterpret_cast<uint4*>(dst)     = *reinterpret_cast<uint4*>(tmp);
    *reinterpret_cast<uint4*>(dst + 8) = *reinterpret_cast<uint4*>(tmp + 8);
}

// ---------------- MFMA GEMM: C[b][co][p] = sum_k A[(b)][co][k] * Bt[b][p][k]
// MODE 0: += bias, write bf16 ybf.  MODE 1: += bias + xres, write fp32 fout.
// Staging via global_load_lds(16B) with pre-swizzled per-lane GLOBAL source:
// LDS dest is linear (base + lane*16); the source element index carries the
// inverse XOR so that LDS content matches swz(row,kb) reads (rule #21).
template<int MODE>
__global__ __launch_bounds__(256) void k_gemm(const u16* __restrict__ A, int aStride,
                                              const u16* __restrict__ Bt,
                                              const float* __restrict__ bias,
                                              u16* __restrict__ ybf,
                                              const float* __restrict__ xres,
                                              float* __restrict__ fout,
                                              int nyTiles)
{
    const int bid = blockIdx.x;
    const int xcd = bid & 7;
    const int r1  = bid >> 3;
    const int px  = xcd * 16 + (r1 & 15);   // p-tile 0..127
    const int r2  = r1 >> 4;
    const int b   = r2 / nyTiles;           // batch
    const int yt  = r2 - b * nyTiles;       // co-tile
    const int co0 = yt * 128;
    const int p0  = px * 128;

    const int t   = threadIdx.x;
    const int l   = t & 63;
    const int wid = t >> 6;
    const int wr  = wid >> 1;      // 0..1 -> row half
    const int wc  = wid & 1;       // 0..1 -> col half
    const int lr  = l & 15;
    const int lg  = l >> 4;        // 0..3

    __shared__ __align__(16) char lds[32768];
    char* AsB = lds;               // [128 rows][64 k] bf16, swizzled content
    char* BsB = lds + 16384;

    f32x4 acc[4][4];
#pragma unroll
    for (int m = 0; m < 4; ++m)
#pragma unroll
        for (int n = 0; n < 4; ++n) acc[m][n] = (f32x4){0.f, 0.f, 0.f, 0.f};

    const u16* Ab  = A  + (size_t)b * aStride;
    const u16* Btb = Bt + (size_t)b * PP * DIM;

    // per-lane source mapping for gld_lds16 (8 rows / wave-issue)
    const int lrow8 = l >> 3;                 // 0..7 within the 8-row group
    const int sl    = l & 7;                  // 16B slot 0..7 within 128B row

    for (int k0 = 0; k0 < DIM; k0 += 64) {
        if (k0) __syncthreads();   // prev iter's LDS reads complete
#pragma unroll
        for (int i = 0; i < 4; ++i) {
            const int rbase = wid * 32 + i * 8;
            const int row   = rbase + lrow8;
            const int elem  = (sl * 8) ^ ((row & 7) << 3);   // inverse swizzle
            gld_lds16(Ab  + (size_t)(co0 + row) * DIM + k0 + elem, AsB + rbase * 128);
            gld_lds16(Btb + (size_t)(p0  + row) * DIM + k0 + elem, BsB + rbase * 128);
        }
        __syncthreads();           // drains vmcnt(0) then barrier -> tiles ready

#pragma unroll
        for (int kk = 0; kk < 64; kk += 32) {
            const int kbyte = kk * 2 + lg * 16;
            bf16x8 av[4], bv[4];
#pragma unroll
            for (int m = 0; m < 4; ++m) {
                const int row = wr * 64 + m * 16 + lr;
                av[m] = *reinterpret_cast<const bf16x8*>(AsB + swz(row, kbyte));
            }
#pragma unroll
            for (int n = 0; n < 4; ++n) {
                const int row = wc * 64 + n * 16 + lr;
                bv[n] = *reinterpret_cast<const bf16x8*>(BsB + swz(row, kbyte));
            }
#pragma unroll
            for (int m = 0; m < 4; ++m)
#pragma unroll
                for (int n = 0; n < 4; ++n)
                    acc[m][n] = __builtin_amdgcn_mfma_f32_16x16x32_bf16(
                        av[m], bv[n], acc[m][n], 0, 0, 0);
        }
    }

    // bias per (m, r): row = wr*64 + m*16 + lg*4 + r
    float bias_r[4][4];
#pragma unroll
    for (int m = 0; m < 4; ++m)
#pragma unroll
        for (int r = 0; r < 4; ++r)
            bias_r[m][r] = bias[co0 + wr * 64 + m * 16 + lg * 4 + r];

    if (MODE == 0) {
        __syncthreads();
        u16* Cs = reinterpret_cast<u16*>(lds);
#pragma unroll
        for (int m = 0; m < 4; ++m)
#pragma unroll
            for (int n = 0; n < 4; ++n)
#pragma unroll
                for (int r = 0; r < 4; ++r) {
                    const int row = wr * 64 + m * 16 + lg * 4 + r;
                    const int col = wc * 64 + n * 16 + lr;
                    Cs[row * 128 + col] = f2bf(acc[m][n][r] + bias_r[m][r]);
                }
        __syncthreads();
        // coalesced store: 16 lanes cover one 256B row segment
        const int rr = t >> 4;          // 0..15
        const int cs = (t & 15) * 8;    // u16 col
#pragma unroll
        for (int j = 0; j < 8; ++j) {
            const int row = j * 16 + rr;
            *reinterpret_cast<uint4*>(&ybf[((size_t)b * DIM3 + co0 + row) * PP + p0 + cs]) =
                *reinterpret_cast<const uint4*>(&Cs[row * 128 + cs]);
        }
    } else {
        // fp32 epilogue via LDS in two 64-row half-passes
        float* Cf = reinterpret_cast<float*>(lds);
#pragma unroll
        for (int h = 0; h < 2; ++h) {
            __syncthreads();
            if (wr == h) {
#pragma unroll
                for (int m = 0; m < 4; ++m)
#pragma unroll
                    for (int n = 0; n < 4; ++n)
#pragma unroll
                        for (int r = 0; r < 4; ++r) {
                            const int lrow = m * 16 + lg * 4 + r;
                            const int col = wc * 64 + n * 16 + lr;
                            Cf[lrow * 128 + col] = acc[m][n][r] + bias_r[m][r];
                        }
            }
            __syncthreads();
            const int rr = t >> 5;          // 0..7
            const int cc = (t & 31) * 4;    // fp32 col
#pragma unroll
            for (int j = 0; j < 8; ++j) {
                const int lrow = j * 8 + rr;
                const int grow = h * 64 + lrow;
                const size_t idx = ((size_t)b * DIM + co0 + grow) * PP + p0 + cc;
                float4 xr = *reinterpret_cast<const float4*>(&xres[idx]);
                float4 cv = *reinterpret_cast<const float4*>(&Cf[lrow * 128 + cc]);
                cv.x += xr.x; cv.y += xr.y; cv.z += xr.z; cv.w += xr.w;
                *reinterpret_cast<float4*>(&fout[idx]) = cv;
            }
        }
    }
}

// ---------------- depthwise 3x3 + bias -> bf16 y2
__global__ __launch_bounds__(256) void k_dw(const u16* __restrict__ y1,
                                            const float* __restrict__ wdw,
                                            const float* __restrict__ bdw,
                                            u16* __restrict__ y2)
{
    const int b  = blockIdx.z;
    const int ch = blockIdx.y;
    const int p  = (blockIdx.x * 256 + (int)threadIdx.x) * 8;
    const int row = p >> 7;
    const int col = p & 127;
    const size_t ib = ((size_t)b * DIM3 + ch) * PP;
    const u16* img = y1 + ib;

    float w9[9];
#pragma unroll
    for (int i = 0; i < 9; ++i) w9[i] = wdw[ch * 9 + i];
    const float bv = bdw[ch];

    float vr[3][10];
#pragma unroll
    for (int dy = 0; dy < 3; ++dy) {
        const int r = row + dy - 1;
        if (r >= 0 && r < HH) {
            const u16* rp = img + r * WW2 + col;
            union { int4 v; u16 u[8]; } cc;
            cc.v = *reinterpret_cast<const int4*>(rp);
#pragma unroll
            for (int j = 0; j < 8; ++j) vr[dy][j + 1] = bf2f(cc.u[j]);
            vr[dy][0] = (col > 0) ? bf2f(rp[-1]) : 0.f;
            vr[dy][9] = (col + 8 < WW2) ? bf2f(rp[8]) : 0.f;
        } else {
#pragma unroll
            for (int j = 0; j < 10; ++j) vr[dy][j] = 0.f;
        }
    }
    union { int4 v; u16 u[8]; } ou;
#pragma unroll
    for (int j = 0; j < 8; ++j) {
        float a = bv;
#pragma unroll
        for (int dy = 0; dy < 3; ++dy)
#pragma unroll
            for (int dx = 0; dx < 3; ++dx)
                a = fmaf(w9[dy * 3 + dx], vr[dy][j + dx], a);
        ou.u[j] = f2bf(a);
    }
    *reinterpret_cast<int4*>(y2 + ib + p) = ou.v;
}

// ---------------- Gram-matrix partials (q.k, q.q, k.k) per batch
__global__ __launch_bounds__(256) void k_dots(const u16* __restrict__ y2,
                                              float* __restrict__ partial)
{
    const int b  = blockIdx.z;
    const int cy = blockIdx.y;
    const int c0 = cy * 24;
    const int p2 = (blockIdx.x * 256 + (int)threadIdx.x) * 2;
    const u16* qb = y2 + (size_t)b * DIM3 * PP + p2;
    const u16* kb = qb + (size_t)DIM * PP;

    float qk[64], qq[8], ks[8];
#pragma unroll
    for (int i = 0; i < 64; ++i) qk[i] = 0.f;
#pragma unroll
    for (int i = 0; i < 8; ++i) { qq[i] = 0.f; ks[i] = 0.f; }

    for (int c = c0; c < c0 + 24; ++c) {
        float q0[8], q1[8], k0[8], k1[8];
#pragma unroll
        for (int n = 0; n < 8; ++n) {
            const unsigned int qv = *reinterpret_cast<const unsigned int*>(qb + (size_t)(n * CPG + c) * PP);
            q0[n] = __uint_as_float(qv << 16);
            q1[n] = __uint_as_float(qv & 0xffff0000u);
            const unsigned int kv = *reinterpret_cast<const unsigned int*>(kb + (size_t)(n * CPG + c) * PP);
            k0[n] = __uint_as_float(kv << 16);
            k1[n] = __uint_as_float(kv & 0xffff0000u);
        }
#pragma unroll
        for (int n = 0; n < 8; ++n) {
#pragma unroll
            for (int m = 0; m < 8; ++m)
                qk[n * 8 + m] += q0[n] * k0[m] + q1[n] * k1[m];
            qq[n] += q0[n] * q0[n] + q1[n] * q1[n];
            ks[n] += k0[n] * k0[n] + k1[n] * k1[n];
        }
    }
    const int wave = (int)threadIdx.x >> 6;
    const int lane = (int)threadIdx.x & 63;
    const size_t rowidx = (size_t)((((b * 2 + cy) * 32 + blockIdx.x) * 4 + wave)) * 80;
#pragma unroll
    for (int i = 0; i < 80; ++i) {
        float v = (i < 64) ? qk[i] : ((i < 72) ? qq[i - 64] : ks[i - 72]);
        v += __shfl_down(v, 32);
        v += __shfl_down(v, 16);
        v += __shfl_down(v, 8);
        v += __shfl_down(v, 4);
        v += __shfl_down(v, 2);
        v += __shfl_down(v, 1);
        if (lane == 0) partial[rowidx + i] = v;
    }
}

// ---------------- reduce partials, normalize, softmax -> attn[b][8][8]
__global__ __launch_bounds__(128) void k_attn(const float* __restrict__ partial,
                                              const float* __restrict__ temp,
                                              float* __restrict__ attn)
{
    const int b = blockIdx.x;
    const int t = threadIdx.x;
    __shared__ float dots[80];
    __shared__ float sc[8][8];
    if (t < 80) {
        float s = 0.f;
        for (int i = 0; i < 256; ++i)
            s += partial[((size_t)b * 256 + i) * 80 + t];
        dots[t] = s;
    }
    __syncthreads();
    if (t < 64) {
        const int n = t >> 3, m = t & 7;
        const float qn = fmaxf(sqrtf(dots[64 + n]), 1e-12f);
        const float km = fmaxf(sqrtf(dots[72 + m]), 1e-12f);
        sc[n][m] = dots[n * 8 + m] / (qn * km) * temp[0];
    }
    __syncthreads();
    if (t < 8) {
        float mx = -3.0e38f;
#pragma unroll
        for (int m = 0; m < 8; ++m) mx = fmaxf(mx, sc[t][m]);
        float e[8], s = 0.f;
#pragma unroll
        for (int m = 0; m < 8; ++m) { e[m] = expf(sc[t][m] - mx); s += e[m]; }
        const float inv = 1.f / s;
#pragma unroll
        for (int m = 0; m < 8; ++m) attn[(b * 8 + t) * 8 + m] = e[m] * inv;
    }
}

// ---------------- Weff[b][co][m*48+c] = sum_n wproj[co][n*48+c]*attn[n][m]  (bf16 out)
__global__ __launch_bounds__(128) void k_weff(const float* __restrict__ attn,
                                              const float* __restrict__ wproj,
                                              u16* __restrict__ weff)
{
    const int b  = blockIdx.y;
    const int co = blockIdx.x;
    const int t  = threadIdx.x;
    __shared__ float a[64];
    if (t < 64) a[t] = attn[b * 64 + t];
    __syncthreads();
    const float* wrow = wproj + (size_t)co * DIM;
    u16* wout = weff + ((size_t)b * DIM + co) * DIM;
    for (int i = t; i < DIM; i += 128) {
        const int m = i / CPG;
        const int c = i - m * CPG;
        float s = 0.f;
#pragma unroll
        for (int n = 0; n < 8; ++n) s += wrow[n * CPG + c] * a[n * 8 + m];
        wout[i] = f2bf(s);
    }
}

extern "C" void kernel_launch(void* const* d_in, const int* in_sizes, int n_in,
                              void* d_out, int out_size, void* d_ws, size_t ws_size,
                              hipStream_t stream)
{
    const float* x      = (const float*)d_in[0];
    const float* temp   = (const float*)d_in[1];
    const float* w_qkv  = (const float*)d_in[2];
    const float* b_qkv  = (const float*)d_in[3];
    const float* w_dw   = (const float*)d_in[4];
    const float* b_dw   = (const float*)d_in[5];
    const float* w_proj = (const float*)d_in[6];
    const float* b_proj = (const float*)d_in[7];
    float* out = (float*)d_out;

    char* ws = (char*)d_ws;
    const size_t SZ_QKV = (size_t)BB * DIM3 * PP * sizeof(u16);  // 150,994,944
    const size_t SZ_XT  = (size_t)BB * PP * DIM * sizeof(u16);   //  50,331,648

    // region 0: [0, SZ_QKV)
    u16* y1 = (u16*)ws;                           // k_gemm<0> -> k_dw, then dead
    float* partial = (float*)ws;                  // 327,680 B (after k_dw)
    float* attn    = (float*)(ws + 327680);       // 1,024 B
    u16*   weffb   = (u16*)(ws + 331776);         // 1,179,648 B (ends 1,511,424)
    u16*   vt      = (u16*)(ws + 2097152);        // 50,331,648 B (ends ~52.4 MB)

    // region 1: [SZ_QKV, SZ_QKV + SZ_QKV)
    u16* y2  = (u16*)(ws + SZ_QKV);               // k_dw onward
    u16* xt  = (u16*)(ws + SZ_QKV);               // pre-k_dw only (aliased, dead before y2 write)
    u16* wbf = (u16*)(ws + SZ_QKV + SZ_XT);       // 884,736 B (pre-k_dw only)

    k_wcvt<<<dim3(DIM3 * DIM / 1024), 256, 0, stream>>>(w_qkv, wbf);
    k_tr_x<<<dim3(PP / 64, DIM / 64, BB), 256, 0, stream>>>(x, xt);
    k_gemm<0><<<dim3(128 * 9 * BB), 256, 0, stream>>>(
        wbf, 0, xt, b_qkv, y1, nullptr, nullptr, 9);
    k_dw<<<dim3(PP / 2048, DIM3, BB), 256, 0, stream>>>(y1, w_dw, b_dw, y2);
    k_dots<<<dim3(32, 2, BB), 256, 0, stream>>>(y2, partial);
    k_attn<<<dim3(BB), 128, 0, stream>>>(partial, temp, attn);
    k_weff<<<dim3(DIM, BB), 128, 0, stream>>>(attn, w_proj, weffb);
    k_tr_v<<<dim3(PP / 64, DIM / 64, BB), 256, 0, stream>>>(y2, vt);
    k_gemm<1><<<dim3(128 * 3 * BB), 256, 0, stream>>>(
        weffb, DIM * DIM, vt, b_proj, nullptr, x, out, 3);
}

// Round 10
// 321.645 us; speedup vs baseline: 2.0748x; 1.2069x over previous
//
#include <hip/hip_runtime.h>
#include <hip/hip_bf16.h>

#define BB 4
#define CPG 48
#define HH 128
#define WW2 128
#define PP 16384
#define DIM 384
#define DIM3 1152

typedef unsigned short u16;
typedef __attribute__((ext_vector_type(8))) short bf16x8;
typedef __attribute__((ext_vector_type(4))) float f32x4;

__device__ __forceinline__ float bf2f(u16 u) {
    return __uint_as_float(((unsigned int)u) << 16);
}
__device__ __forceinline__ u16 f2bf(float f) {
    unsigned int u = __float_as_uint(f);
    unsigned int r = (u + 0x7fffu + ((u >> 16) & 1u)) >> 16;
    return (u16)r;
}

// LDS swizzle: rows are 128B; XOR the 16B-slot index with (row&7) to spread banks
__device__ __forceinline__ int swz(int row, int kb) {
    return row * 128 + (kb ^ ((row & 7) << 4));
}

// async global->LDS, 16B per lane; LDS dest = wave-uniform base + lane*16
__device__ __forceinline__ void gld_lds16(const u16* g, char* l) {
    __builtin_amdgcn_global_load_lds(
        (const __attribute__((address_space(1))) void*)g,
        (__attribute__((address_space(3))) void*)l, 16, 0, 0);
}

// ---------------- convert w_qkv fp32 -> bf16
__global__ __launch_bounds__(256) void k_wcvt(const float* __restrict__ w,
                                              u16* __restrict__ wbf)
{
    const int i4 = (blockIdx.x * 256 + threadIdx.x) * 4;
    float4 v = *reinterpret_cast<const float4*>(w + i4);
    ushort4 s;
    s.x = f2bf(v.x); s.y = f2bf(v.y); s.z = f2bf(v.z); s.w = f2bf(v.w);
    *reinterpret_cast<ushort4*>(wbf + i4) = s;
}

// ---------------- transpose x [b][k=384][p] fp32 -> Xt [b][p][k=384] bf16
__global__ __launch_bounds__(256) void k_tr_x(const float* __restrict__ x,
                                              u16* __restrict__ xt)
{
    const int b = blockIdx.z;
    const int k0 = blockIdx.y * 64;
    const int p0 = blockIdx.x * 64;
    const int t = threadIdx.x;
    __shared__ u16 T[64][68];

    const int kl = t >> 4;          // 0..15
    const int pl = (t & 15) * 4;    // 0..60
#pragma unroll
    for (int ks = 0; ks < 4; ++ks) {
        const int k = ks * 16 + kl;
        float4 v = *reinterpret_cast<const float4*>(&x[((size_t)b * DIM + k0 + k) * PP + p0 + pl]);
        ushort4 s;
        s.x = f2bf(v.x); s.y = f2bf(v.y); s.z = f2bf(v.z); s.w = f2bf(v.w);
        *reinterpret_cast<ushort4*>(&T[k][pl]) = s;
    }
    __syncthreads();
    const int pr = t >> 2;          // 0..63
    const int kg = (t & 3) * 16;    // 0,16,32,48
    __align__(16) u16 tmp[16];
#pragma unroll
    for (int j = 0; j < 16; ++j) tmp[j] = T[kg + j][pr];
    u16* dst = xt + ((size_t)b * PP + p0 + pr) * DIM + k0 + kg;
    *reinterpret_cast<uint4*>(dst)     = *reinterpret_cast<uint4*>(tmp);
    *reinterpret_cast<uint4*>(dst + 8) = *reinterpret_cast<uint4*>(tmp + 8);
}

// ---------------- transpose v part of y2 [b][768+c][p] bf16 -> Vt [b][p][c=384] bf16
__global__ __launch_bounds__(256) void k_tr_v(const u16* __restrict__ y2,
                                              u16* __restrict__ vt)
{
    const int b = blockIdx.z;
    const int c0 = blockIdx.y * 64;
    const int p0 = blockIdx.x * 64;
    const int t = threadIdx.x;
    __shared__ u16 T[64][68];

    const int cl = t >> 4;
    const int pl = (t & 15) * 4;
#pragma unroll
    for (int cs = 0; cs < 4; ++cs) {
        const int c = cs * 16 + cl;
        ushort4 v = *reinterpret_cast<const ushort4*>(
            &y2[((size_t)b * DIM3 + 2 * DIM + c0 + c) * PP + p0 + pl]);
        *reinterpret_cast<ushort4*>(&T[c][pl]) = v;
    }
    __syncthreads();
    const int pr = t >> 2;
    const int kg = (t & 3) * 16;
    __align__(16) u16 tmp[16];
#pragma unroll
    for (int j = 0; j < 16; ++j) tmp[j] = T[kg + j][pr];
    u16* dst = vt + ((size_t)b * PP + p0 + pr) * DIM + c0 + kg;
    *reinterpret_cast<uint4*>(dst)     = *reinterpret_cast<uint4*>(tmp);
    *reinterpret_cast<uint4*>(dst + 8) = *reinterpret_cast<uint4*>(tmp + 8);
}

// ---------------- MFMA GEMM: C[b][co][p] = sum_k A[(b)][co][k] * Bt[b][p][k]
// MODE 0: += bias, write bf16 ybf.  MODE 1: += bias + xres, write fp32 fout.
// Staging via global_load_lds(16B) with pre-swizzled per-lane GLOBAL source.
template<int MODE>
__global__ __launch_bounds__(256) void k_gemm(const u16* __restrict__ A, int aStride,
                                              const u16* __restrict__ Bt,
                                              const float* __restrict__ bias,
                                              u16* __restrict__ ybf,
                                              const float* __restrict__ xres,
                                              float* __restrict__ fout,
                                              int nyTiles)
{
    const int bid = blockIdx.x;
    const int xcd = bid & 7;
    const int r1  = bid >> 3;
    const int px  = xcd * 16 + (r1 & 15);   // p-tile 0..127
    const int r2  = r1 >> 4;
    const int b   = r2 / nyTiles;           // batch
    const int yt  = r2 - b * nyTiles;       // co-tile
    const int co0 = yt * 128;
    const int p0  = px * 128;

    const int t   = threadIdx.x;
    const int l   = t & 63;
    const int wid = t >> 6;
    const int wr  = wid >> 1;      // 0..1 -> row half
    const int wc  = wid & 1;       // 0..1 -> col half
    const int lr  = l & 15;
    const int lg  = l >> 4;        // 0..3

    __shared__ __align__(16) char lds[32768];
    char* AsB = lds;               // [128 rows][64 k] bf16, swizzled content
    char* BsB = lds + 16384;

    f32x4 acc[4][4];
#pragma unroll
    for (int m = 0; m < 4; ++m)
#pragma unroll
        for (int n = 0; n < 4; ++n) acc[m][n] = (f32x4){0.f, 0.f, 0.f, 0.f};

    const u16* Ab  = A  + (size_t)b * aStride;
    const u16* Btb = Bt + (size_t)b * PP * DIM;

    // per-lane source mapping for gld_lds16 (8 rows / wave-issue)
    const int lrow8 = l >> 3;                 // 0..7 within the 8-row group
    const int sl    = l & 7;                  // 16B slot 0..7 within 128B row

    for (int k0 = 0; k0 < DIM; k0 += 64) {
        if (k0) __syncthreads();   // prev iter's LDS reads complete
#pragma unroll
        for (int i = 0; i < 4; ++i) {
            const int rbase = wid * 32 + i * 8;
            const int row   = rbase + lrow8;
            const int elem  = (sl * 8) ^ ((row & 7) << 3);   // inverse swizzle
            gld_lds16(Ab  + (size_t)(co0 + row) * DIM + k0 + elem, AsB + rbase * 128);
            gld_lds16(Btb + (size_t)(p0  + row) * DIM + k0 + elem, BsB + rbase * 128);
        }
        __syncthreads();           // drains vmcnt(0) then barrier -> tiles ready

#pragma unroll
        for (int kk = 0; kk < 64; kk += 32) {
            const int kbyte = kk * 2 + lg * 16;
            bf16x8 av[4], bv[4];
#pragma unroll
            for (int m = 0; m < 4; ++m) {
                const int row = wr * 64 + m * 16 + lr;
                av[m] = *reinterpret_cast<const bf16x8*>(AsB + swz(row, kbyte));
            }
#pragma unroll
            for (int n = 0; n < 4; ++n) {
                const int row = wc * 64 + n * 16 + lr;
                bv[n] = *reinterpret_cast<const bf16x8*>(BsB + swz(row, kbyte));
            }
#pragma unroll
            for (int m = 0; m < 4; ++m)
#pragma unroll
                for (int n = 0; n < 4; ++n)
                    acc[m][n] = __builtin_amdgcn_mfma_f32_16x16x32_bf16(
                        av[m], bv[n], acc[m][n], 0, 0, 0);
        }
    }

    // bias per (m, r): row = wr*64 + m*16 + lg*4 + r
    float bias_r[4][4];
#pragma unroll
    for (int m = 0; m < 4; ++m)
#pragma unroll
        for (int r = 0; r < 4; ++r)
            bias_r[m][r] = bias[co0 + wr * 64 + m * 16 + lg * 4 + r];

    if (MODE == 0) {
        __syncthreads();
        u16* Cs = reinterpret_cast<u16*>(lds);
#pragma unroll
        for (int m = 0; m < 4; ++m)
#pragma unroll
            for (int n = 0; n < 4; ++n)
#pragma unroll
                for (int r = 0; r < 4; ++r) {
                    const int row = wr * 64 + m * 16 + lg * 4 + r;
                    const int col = wc * 64 + n * 16 + lr;
                    Cs[row * 128 + col] = f2bf(acc[m][n][r] + bias_r[m][r]);
                }
        __syncthreads();
        // coalesced store: 16 lanes cover one 256B row segment
        const int rr = t >> 4;          // 0..15
        const int cs = (t & 15) * 8;    // u16 col
#pragma unroll
        for (int j = 0; j < 8; ++j) {
            const int row = j * 16 + rr;
            *reinterpret_cast<uint4*>(&ybf[((size_t)b * DIM3 + co0 + row) * PP + p0 + cs]) =
                *reinterpret_cast<const uint4*>(&Cs[row * 128 + cs]);
        }
    } else {
        // fp32 epilogue via LDS in two 64-row half-passes
        float* Cf = reinterpret_cast<float*>(lds);
#pragma unroll
        for (int h = 0; h < 2; ++h) {
            __syncthreads();
            if (wr == h) {
#pragma unroll
                for (int m = 0; m < 4; ++m)
#pragma unroll
                    for (int n = 0; n < 4; ++n)
#pragma unroll
                        for (int r = 0; r < 4; ++r) {
                            const int lrow = m * 16 + lg * 4 + r;
                            const int col = wc * 64 + n * 16 + lr;
                            Cf[lrow * 128 + col] = acc[m][n][r] + bias_r[m][r];
                        }
            }
            __syncthreads();
            const int rr = t >> 5;          // 0..7
            const int cc = (t & 31) * 4;    // fp32 col
#pragma unroll
            for (int j = 0; j < 8; ++j) {
                const int lrow = j * 8 + rr;
                const int grow = h * 64 + lrow;
                const size_t idx = ((size_t)b * DIM + co0 + grow) * PP + p0 + cc;
                float4 xr = *reinterpret_cast<const float4*>(&xres[idx]);
                float4 cv = *reinterpret_cast<const float4*>(&Cf[lrow * 128 + cc]);
                cv.x += xr.x; cv.y += xr.y; cv.z += xr.z; cv.w += xr.w;
                *reinterpret_cast<float4*>(&fout[idx]) = cv;
            }
        }
    }
}

// ---------------- depthwise 3x3 + bias -> bf16 y2
// One block = one (b, ch) 128x128 image. 16x16 strips of 8x8 px per thread.
// Column halos via lane shuffles; sliding 3-row register window.
#define LOADROW(arr, r)                                                        \
    {                                                                          \
        const int r_ = (r);                                                    \
        if (r_ >= 0 && r_ < HH) {                                              \
            union { int4 v; u16 u[8]; } cc_;                                   \
            cc_.v = *reinterpret_cast<const int4*>(img + r_ * WW2 + c0);       \
            arr[1] = bf2f(cc_.u[0]); arr[2] = bf2f(cc_.u[1]);                  \
            arr[3] = bf2f(cc_.u[2]); arr[4] = bf2f(cc_.u[3]);                  \
            arr[5] = bf2f(cc_.u[4]); arr[6] = bf2f(cc_.u[5]);                  \
            arr[7] = bf2f(cc_.u[6]); arr[8] = bf2f(cc_.u[7]);                  \
        } else {                                                               \
            arr[1] = 0.f; arr[2] = 0.f; arr[3] = 0.f; arr[4] = 0.f;            \
            arr[5] = 0.f; arr[6] = 0.f; arr[7] = 0.f; arr[8] = 0.f;            \
        }                                                                      \
        float lf_ = __shfl(arr[8], t - 1);                                     \
        float rt_ = __shfl(arr[1], t + 1);                                     \
        arr[0] = (tc > 0)  ? lf_ : 0.f;                                        \
        arr[9] = (tc < 15) ? rt_ : 0.f;                                        \
    }

__global__ __launch_bounds__(256) void k_dw(const u16* __restrict__ y1,
                                            const float* __restrict__ wdw,
                                            const float* __restrict__ bdw,
                                            u16* __restrict__ y2)
{
    const int ch = blockIdx.x;
    const int b  = blockIdx.y;
    const size_t ib = ((size_t)b * DIM3 + ch) * PP;
    const u16* img = y1 + ib;

    const int t  = (int)threadIdx.x;
    const int tc = t & 15;        // col strip 0..15
    const int tr = t >> 4;        // row band 0..15
    const int c0 = tc * 8;
    const int r0 = tr * 8;

    float w9[9];
#pragma unroll
    for (int i = 0; i < 9; ++i) w9[i] = wdw[ch * 9 + i];
    const float bv = bdw[ch];

    float A[10], B[10], C[10];
    LOADROW(A, r0 - 1);
    LOADROW(B, r0);

#pragma unroll
    for (int j = 0; j < 8; ++j) {
        LOADROW(C, r0 + j + 1);
        union { int4 v; u16 u[8]; } ou;
#pragma unroll
        for (int c = 0; c < 8; ++c) {
            float a = bv;
            a = fmaf(w9[0], A[c],     a);
            a = fmaf(w9[1], A[c + 1], a);
            a = fmaf(w9[2], A[c + 2], a);
            a = fmaf(w9[3], B[c],     a);
            a = fmaf(w9[4], B[c + 1], a);
            a = fmaf(w9[5], B[c + 2], a);
            a = fmaf(w9[6], C[c],     a);
            a = fmaf(w9[7], C[c + 1], a);
            a = fmaf(w9[8], C[c + 2], a);
            ou.u[c] = f2bf(a);
        }
        *reinterpret_cast<int4*>(y2 + ib + (r0 + j) * WW2 + c0) = ou.v;
#pragma unroll
        for (int q = 0; q < 10; ++q) { A[q] = B[q]; B[q] = C[q]; }
    }
}

// ---------------- Gram-matrix partials (q.k, q.q, k.k) per batch
__global__ __launch_bounds__(256) void k_dots(const u16* __restrict__ y2,
                                              float* __restrict__ partial)
{
    const int b  = blockIdx.z;
    const int cy = blockIdx.y;
    const int c0 = cy * 24;
    const int p2 = (blockIdx.x * 256 + (int)threadIdx.x) * 2;
    const u16* qb = y2 + (size_t)b * DIM3 * PP + p2;
    const u16* kb = qb + (size_t)DIM * PP;

    float qk[64], qq[8], ks[8];
#pragma unroll
    for (int i = 0; i < 64; ++i) qk[i] = 0.f;
#pragma unroll
    for (int i = 0; i < 8; ++i) { qq[i] = 0.f; ks[i] = 0.f; }

    for (int c = c0; c < c0 + 24; ++c) {
        float q0[8], q1[8], k0[8], k1[8];
#pragma unroll
        for (int n = 0; n < 8; ++n) {
            const unsigned int qv = *reinterpret_cast<const unsigned int*>(qb + (size_t)(n * CPG + c) * PP);
            q0[n] = __uint_as_float(qv << 16);
            q1[n] = __uint_as_float(qv & 0xffff0000u);
            const unsigned int kv = *reinterpret_cast<const unsigned int*>(kb + (size_t)(n * CPG + c) * PP);
            k0[n] = __uint_as_float(kv << 16);
            k1[n] = __uint_as_float(kv & 0xffff0000u);
        }
#pragma unroll
        for (int n = 0; n < 8; ++n) {
#pragma unroll
            for (int m = 0; m < 8; ++m)
                qk[n * 8 + m] += q0[n] * k0[m] + q1[n] * k1[m];
            qq[n] += q0[n] * q0[n] + q1[n] * q1[n];
            ks[n] += k0[n] * k0[n] + k1[n] * k1[n];
        }
    }
    const int wave = (int)threadIdx.x >> 6;
    const int lane = (int)threadIdx.x & 63;
    const size_t rowidx = (size_t)((((b * 2 + cy) * 32 + blockIdx.x) * 4 + wave)) * 80;
#pragma unroll
    for (int i = 0; i < 80; ++i) {
        float v = (i < 64) ? qk[i] : ((i < 72) ? qq[i - 64] : ks[i - 72]);
        v += __shfl_down(v, 32);
        v += __shfl_down(v, 16);
        v += __shfl_down(v, 8);
        v += __shfl_down(v, 4);
        v += __shfl_down(v, 2);
        v += __shfl_down(v, 1);
        if (lane == 0) partial[rowidx + i] = v;
    }
}

// ---------------- reduce partials, normalize, softmax -> attn[b][8][8]
__global__ __launch_bounds__(128) void k_attn(const float* __restrict__ partial,
                                              const float* __restrict__ temp,
                                              float* __restrict__ attn)
{
    const int b = blockIdx.x;
    const int t = threadIdx.x;
    __shared__ float dots[80];
    __shared__ float sc[8][8];
    if (t < 80) {
        float s = 0.f;
        for (int i = 0; i < 256; ++i)
            s += partial[((size_t)b * 256 + i) * 80 + t];
        dots[t] = s;
    }
    __syncthreads();
    if (t < 64) {
        const int n = t >> 3, m = t & 7;
        const float qn = fmaxf(sqrtf(dots[64 + n]), 1e-12f);
        const float km = fmaxf(sqrtf(dots[72 + m]), 1e-12f);
        sc[n][m] = dots[n * 8 + m] / (qn * km) * temp[0];
    }
    __syncthreads();
    if (t < 8) {
        float mx = -3.0e38f;
#pragma unroll
        for (int m = 0; m < 8; ++m) mx = fmaxf(mx, sc[t][m]);
        float e[8], s = 0.f;
#pragma unroll
        for (int m = 0; m < 8; ++m) { e[m] = expf(sc[t][m] - mx); s += e[m]; }
        const float inv = 1.f / s;
#pragma unroll
        for (int m = 0; m < 8; ++m) attn[(b * 8 + t) * 8 + m] = e[m] * inv;
    }
}

// ---------------- Weff[b][co][m*48+c] = sum_n wproj[co][n*48+c]*attn[n][m]  (bf16 out)
__global__ __launch_bounds__(128) void k_weff(const float* __restrict__ attn,
                                              const float* __restrict__ wproj,
                                              u16* __restrict__ weff)
{
    const int b  = blockIdx.y;
    const int co = blockIdx.x;
    const int t  = threadIdx.x;
    __shared__ float a[64];
    if (t < 64) a[t] = attn[b * 64 + t];
    __syncthreads();
    const float* wrow = wproj + (size_t)co * DIM;
    u16* wout = weff + ((size_t)b * DIM + co) * DIM;
    for (int i = t; i < DIM; i += 128) {
        const int m = i / CPG;
        const int c = i - m * CPG;
        float s = 0.f;
#pragma unroll
        for (int n = 0; n < 8; ++n) s += wrow[n * CPG + c] * a[n * 8 + m];
        wout[i] = f2bf(s);
    }
}

extern "C" void kernel_launch(void* const* d_in, const int* in_sizes, int n_in,
                              void* d_out, int out_size, void* d_ws, size_t ws_size,
                              hipStream_t stream)
{
    const float* x      = (const float*)d_in[0];
    const float* temp   = (const float*)d_in[1];
    const float* w_qkv  = (const float*)d_in[2];
    const float* b_qkv  = (const float*)d_in[3];
    const float* w_dw   = (const float*)d_in[4];
    const float* b_dw   = (const float*)d_in[5];
    const float* w_proj = (const float*)d_in[6];
    const float* b_proj = (const float*)d_in[7];
    float* out = (float*)d_out;

    char* ws = (char*)d_ws;
    const size_t SZ_QKV = (size_t)BB * DIM3 * PP * sizeof(u16);  // 150,994,944
    const size_t SZ_XT  = (size_t)BB * PP * DIM * sizeof(u16);   //  50,331,648

    // region 0: [0, SZ_QKV)
    u16* y1 = (u16*)ws;                           // k_gemm<0> -> k_dw, then dead
    float* partial = (float*)ws;                  // 327,680 B (after k_dw)
    float* attn    = (float*)(ws + 327680);       // 1,024 B
    u16*   weffb   = (u16*)(ws + 331776);         // 1,179,648 B (ends 1,511,424)
    u16*   vt      = (u16*)(ws + 2097152);        // 50,331,648 B (ends ~52.4 MB)

    // region 1: [SZ_QKV, SZ_QKV + SZ_QKV)
    u16* y2  = (u16*)(ws + SZ_QKV);               // k_dw onward
    u16* xt  = (u16*)(ws + SZ_QKV);               // pre-k_dw only (aliased, dead before y2 write)
    u16* wbf = (u16*)(ws + SZ_QKV + SZ_XT);       // 884,736 B (pre-k_dw only)

    k_wcvt<<<dim3(DIM3 * DIM / 1024), 256, 0, stream>>>(w_qkv, wbf);
    k_tr_x<<<dim3(PP / 64, DIM / 64, BB), 256, 0, stream>>>(x, xt);
    k_gemm<0><<<dim3(128 * 9 * BB), 256, 0, stream>>>(
        wbf, 0, xt, b_qkv, y1, nullptr, nullptr, 9);
    k_dw<<<dim3(DIM3, BB), 256, 0, stream>>>(y1, w_dw, b_dw, y2);
    k_dots<<<dim3(32, 2, BB), 256, 0, stream>>>(y2, partial);
    k_attn<<<dim3(BB), 128, 0, stream>>>(partial, temp, attn);
    k_weff<<<dim3(DIM, BB), 128, 0, stream>>>(attn, w_proj, weffb);
    k_tr_v<<<dim3(PP / 64, DIM / 64, BB), 256, 0, stream>>>(y2, vt);
    k_gemm<1><<<dim3(128 * 3 * BB), 256, 0, stream>>>(
        weffb, DIM * DIM, vt, b_proj, nullptr, x, out, 3);
}